// Round 1
// baseline (71.865 us; speedup 1.0000x reference)
//
#include <hip/hip_runtime.h>

// AdderNet forward: out[n,h,w,f] = sum_{dh,dw,c} |Xpad[n,h+dh,w+dw,c] - F[f,dh,dw,c]|
// N=8, H=W=32, C=32, c_out=64, k=3, pad=1, stride=1. All fp32.
//
// Grid: 512 blocks = (n:8, h:32, fhalf:2). Block: 256 threads = (w:32, fg:8).
// Each thread computes 4 outputs: fixed (n,h,w), filters fhalf*32 + fg*4 .. +3.
// X rows staged in LDS with stride-36 padding (4-way worst bank conflict);
// 32 filters staged in LDS; F reads are 2-address/wave (free broadcast).

#define BLOCK 256

__global__ __launch_bounds__(256, 2) void adder_fwd(const float* __restrict__ X,
                                                    const float* __restrict__ Fg,
                                                    float* __restrict__ out) {
    __shared__ float Xs[3 * 34 * 36];   // [r][wc][c] : c stride 1, wc stride 36, r stride 34*36
    __shared__ float Fs[32 * 288];      // [j][(dh*3+dw)*32 + c]

    const int b = blockIdx.x;
    const int fhalf = b & 1;
    const int h = (b >> 1) & 31;
    const int n = b >> 6;
    const int tid = threadIdx.x;

    // ---- stage 32 filters: 9216 floats = 2304 float4, 9 per thread
    {
        const float4* src = (const float4*)(Fg + (size_t)fhalf * (32 * 288));
        float4* dst = (float4*)Fs;
        #pragma unroll
        for (int i = 0; i < 9; ++i) dst[tid + BLOCK * i] = src[tid + BLOCK * i];
    }

    // ---- stage X tile: rows h-1..h+1, w -1..32, zero padded. 3*34*8 = 816 float4
    {
        #pragma unroll
        for (int i = 0; i < 4; ++i) {
            int idx = tid + BLOCK * i;          // float4 slot
            if (idx < 816) {
                int c4 = idx & 7;
                int t  = idx >> 3;              // 0..101 = r*34 + wc
                int wc = t % 34;
                int r  = t / 34;
                int hr = h + r - 1;
                int w  = wc - 1;
                float4 v = make_float4(0.f, 0.f, 0.f, 0.f);
                if ((unsigned)hr < 32u && (unsigned)w < 32u) {
                    v = ((const float4*)(X + (((size_t)n * 32 + hr) * 32 + w) * 32))[c4];
                }
                ((float4*)(Xs + (r * 34 + wc) * 36))[c4] = v;
            }
        }
    }
    __syncthreads();

    const int w  = tid & 31;
    const int fg = tid >> 5;   // 0..7

    float4 a0 = make_float4(0.f, 0.f, 0.f, 0.f);
    float4 a1 = make_float4(0.f, 0.f, 0.f, 0.f);
    float4 a2 = make_float4(0.f, 0.f, 0.f, 0.f);
    float4 a3 = make_float4(0.f, 0.f, 0.f, 0.f);

    #pragma unroll
    for (int r = 0; r < 3; ++r) {
        #pragma unroll
        for (int dw = 0; dw < 3; ++dw) {
            const float4* xp = (const float4*)(Xs + (r * 34 + w + dw) * 36);
            const float*  fb = Fs + (fg * 4) * 288 + (r * 3 + dw) * 32;
            #pragma unroll
            for (int c4 = 0; c4 < 8; ++c4) {
                float4 xv = xp[c4];
                float4 f0 = ((const float4*)(fb + 0 * 288))[c4];
                float4 f1 = ((const float4*)(fb + 1 * 288))[c4];
                float4 f2 = ((const float4*)(fb + 2 * 288))[c4];
                float4 f3 = ((const float4*)(fb + 3 * 288))[c4];
                a0.x += fabsf(xv.x - f0.x); a0.y += fabsf(xv.y - f0.y);
                a0.z += fabsf(xv.z - f0.z); a0.w += fabsf(xv.w - f0.w);
                a1.x += fabsf(xv.x - f1.x); a1.y += fabsf(xv.y - f1.y);
                a1.z += fabsf(xv.z - f1.z); a1.w += fabsf(xv.w - f1.w);
                a2.x += fabsf(xv.x - f2.x); a2.y += fabsf(xv.y - f2.y);
                a2.z += fabsf(xv.z - f2.z); a2.w += fabsf(xv.w - f2.w);
                a3.x += fabsf(xv.x - f3.x); a3.y += fabsf(xv.y - f3.y);
                a3.z += fabsf(xv.z - f3.z); a3.w += fabsf(xv.w - f3.w);
            }
        }
    }

    float4 res;
    res.x = (a0.x + a0.y) + (a0.z + a0.w);
    res.y = (a1.x + a1.y) + (a1.z + a1.w);
    res.z = (a2.x + a2.y) + (a2.z + a2.w);
    res.w = (a3.x + a3.y) + (a3.z + a3.w);

    // out[((n*32+h)*32+w)*64 + fhalf*32 + fg*4 .. +3] as one float4
    float4* o4 = (float4*)out;
    o4[(((size_t)n * 32 + h) * 32 + w) * 16 + fhalf * 8 + fg] = res;
}

extern "C" void kernel_launch(void* const* d_in, const int* in_sizes, int n_in,
                              void* d_out, int out_size, void* d_ws, size_t ws_size,
                              hipStream_t stream) {
    const float* X = (const float*)d_in[0];
    const float* F = (const float*)d_in[1];
    float* out = (float*)d_out;
    adder_fwd<<<dim3(512), dim3(256), 0, stream>>>(X, F, out);
}

// Round 2
// 69.450 us; speedup vs baseline: 1.0348x; 1.0348x over previous
//
#include <hip/hip_runtime.h>

// AdderNet forward: out[n,h,w,f] = sum_{dh,dw,c} |Xpad[n,h+dh,w+dw,c] - F[f,dh,dw,c]|
// N=8, H=W=32, C=32, c_out=64, k=3, pad=1. fp32.
//
// R2: filter operand moved LDS -> SGPR (wave-uniform filter indices).
// Grid 512 = (n:8, hpair:16, fq:4). Block 256 = 4 waves.
// Wave = 64 lanes = (hh:2, w:32) spatial positions, all lanes share the same
// 4 filters (fq*16 + wave*4 ..+3) -> filter loads are scalar (s_load), VALU
// reads them as SGPR operands. LDS holds only the X tile:
// 4 rows (h0-1..h0+2) x 34 wpos x 32 c, wpos stride 36 floats (bank spread).
// Per wave: 72 ds_read_b128 + 2304 VALU  (was 360 ds_read_b128).

#define BLOCK 256

__global__ __launch_bounds__(256, 2) void adder_fwd(const float* __restrict__ X,
                                                    const float* __restrict__ Fg,
                                                    float* __restrict__ out) {
    __shared__ float Xs[4 * 34 * 36];   // [row 0..3][wpos 0..33][c 0..31], wpos stride 36

    const int b = blockIdx.x;
    const int fq = b & 3;            // filter quarter (16 filters)
    const int hp = (b >> 2) & 15;    // h pair
    const int n = b >> 6;
    const int h0 = hp * 2;
    const int tid = threadIdx.x;

    // ---- stage X tile: rows h0-1..h0+2, w -1..32, zero padded. 4*34*8 = 1088 float4
    #pragma unroll
    for (int i = 0; i < 5; ++i) {
        int idx = tid + BLOCK * i;          // float4 slot
        if (idx < 1088) {
            int c4 = idx & 7;
            int t  = idx >> 3;              // 0..135 = rr*34 + wc
            int wc = t % 34;
            int rr = t / 34;                // 0..3
            int hr = h0 + rr - 1;
            int gw = wc - 1;
            float4 v = make_float4(0.f, 0.f, 0.f, 0.f);
            if ((unsigned)hr < 32u && (unsigned)gw < 32u) {
                v = ((const float4*)(X + (((size_t)n * 32 + hr) * 32 + gw) * 32))[c4];
            }
            ((float4*)(Xs + (rr * 34 + wc) * 36))[c4] = v;
        }
    }
    __syncthreads();

    const int w    = tid & 31;
    const int hh   = (tid >> 5) & 1;
    // wave id — wave-uniform by construction; readfirstlane makes it provably
    // uniform so the filter loads select the scalar path (s_load).
    const int wave = __builtin_amdgcn_readfirstlane(tid >> 6);
    const int f0   = fq * 16 + wave * 4;

    const float* fb = Fg + (size_t)f0 * 288;   // 4 filters x 288, wave-uniform base

    float a0 = 0.f, a1 = 0.f, a2 = 0.f, a3 = 0.f;

    #pragma unroll
    for (int r = 0; r < 3; ++r) {
        #pragma unroll
        for (int dw = 0; dw < 3; ++dw) {
            const float4* xp = (const float4*)(Xs + ((hh + r) * 34 + (w + dw)) * 36);
            const float*  ftap = fb + (r * 3 + dw) * 32;
            #pragma unroll
            for (int c4 = 0; c4 < 8; ++c4) {
                float4 xv = xp[c4];
                float4 f0v = ((const float4*)(ftap + 0 * 288))[c4];
                float4 f1v = ((const float4*)(ftap + 1 * 288))[c4];
                float4 f2v = ((const float4*)(ftap + 2 * 288))[c4];
                float4 f3v = ((const float4*)(ftap + 3 * 288))[c4];
                a0 += fabsf(xv.x - f0v.x) + fabsf(xv.y - f0v.y)
                    + fabsf(xv.z - f0v.z) + fabsf(xv.w - f0v.w);
                a1 += fabsf(xv.x - f1v.x) + fabsf(xv.y - f1v.y)
                    + fabsf(xv.z - f1v.z) + fabsf(xv.w - f1v.w);
                a2 += fabsf(xv.x - f2v.x) + fabsf(xv.y - f2v.y)
                    + fabsf(xv.z - f2v.z) + fabsf(xv.w - f2v.w);
                a3 += fabsf(xv.x - f3v.x) + fabsf(xv.y - f3v.y)
                    + fabsf(xv.z - f3v.z) + fabsf(xv.w - f3v.w);
            }
        }
    }

    // out[((n*32 + h0+hh)*32 + w)*64 + f0 .. f0+3] as one float4
    float4* o4 = (float4*)out;
    o4[(((size_t)n * 32 + h0 + hh) * 32 + w) * 16 + (f0 >> 2)] =
        make_float4(a0, a1, a2, a3);
}

extern "C" void kernel_launch(void* const* d_in, const int* in_sizes, int n_in,
                              void* d_out, int out_size, void* d_ws, size_t ws_size,
                              hipStream_t stream) {
    const float* X = (const float*)d_in[0];
    const float* F = (const float*)d_in[1];
    float* out = (float*)d_out;
    adder_fwd<<<dim3(512), dim3(256), 0, stream>>>(X, F, out);
}